// Round 5
// baseline (284.259 us; speedup 1.0000x reference)
//
#include <hip/hip_runtime.h>

// NeuromodulatedAttention — MI355X (gfx950), round 5
//
// ALGEBRA: (1) dopamine/serotonin "mod" is a per-row constant added before the
// per-row mean/std normalization -> cancels exactly (both MLPs are dead code).
// (2) the mean subtraction is a per-row constant inside softmax -> also cancels.
// Effective:  out = softmax( S * istd_row ) @ V,
//   S = Q K^T / sqrt(512),  istd_row = 1/(std(S_row, ddof=1) + 1e-6).
//
// Round-5 structure (round-4 was in-flight-bytes limited at distance-1
// prefetch, and burned 134 MB HBM on the Opart round-trip):
//   K1 cast_k:      K fp32 -> bf16            (Q is staged from fp32 in K3)
//   K2 transpose_v: V fp32 -> Vt bf16 [b][d][s]
//   K3 stats2: grid (64 qt, 8 kc, 4 b)=2048 blocks. Wave = 64 k-rows, 2 accs
//      (32 AGPR), distance-4 register prefetch. Writes S f16 + stats atomics.
//   K4 pv2: grid (64 qt, 4 dsl, 4 b)=1024 blocks, d-SPLIT (owns all 2048 k in
//      four 512-k chunks) -> writes out directly, fp32 accumulate, block-local
//      denominator. 1 acc (16 AGPR) => distance-8 prefetch at occupancy 4.
//      No Opart, no reduce kernel. S re-read x4 is L3-resident.

#define BB 4
#define SS 2048
#define DD 512
#define SCALE 0.044194173824159216f  // 1/sqrt(512)
#define LOG2E 1.4426950408889634f

typedef __bf16 bf16;
typedef _Float16 f16;
typedef bf16 bf16x2 __attribute__((ext_vector_type(2)));
typedef bf16 bf16x4 __attribute__((ext_vector_type(4)));
typedef bf16 bf16x8 __attribute__((ext_vector_type(8)));
typedef f16  f16x8  __attribute__((ext_vector_type(8)));
typedef float f32x16 __attribute__((ext_vector_type(16)));

// XOR-swizzled element index inside a 32x512 bf16 LDS tile.
__device__ __forceinline__ int sw(int row, int col) {
  return row * 512 + ((((col >> 3) ^ (row & 7))) << 3) + (col & 7);
}

// ---------------- K1: cast K to bf16 ----------------

__global__ void cast_k_kernel(const float* __restrict__ K, bf16* __restrict__ Kb) {
  size_t i = ((size_t)blockIdx.x * 256 + threadIdx.x) * 8;
  float4 b0 = *(const float4*)(K + i);
  float4 b1 = *(const float4*)(K + i + 4);
  bf16x8 ka = { (bf16)b0.x, (bf16)b0.y, (bf16)b0.z, (bf16)b0.w,
                (bf16)b1.x, (bf16)b1.y, (bf16)b1.z, (bf16)b1.w };
  *(bf16x8*)(Kb + i) = ka;
}

// ---------------- K2: V [b][s][d] fp32 -> Vt [b][d][s] bf16 ----------------

__global__ void transpose_v_kernel(const float* __restrict__ V, bf16* __restrict__ Vt) {
  __shared__ bf16 tile[64][80];
  const int b = blockIdx.z;
  const int s0 = blockIdx.x * 64, d0 = blockIdx.y * 64;
  const int t = threadIdx.x;
  const int r16 = t >> 4;
  const int c4  = (t & 15) * 4;
#pragma unroll
  for (int i = 0; i < 4; ++i) {
    int r = i * 16 + r16;
    float4 v = *(const float4*)&V[((size_t)b * SS + s0 + r) * DD + d0 + c4];
    tile[c4 + 0][r] = (bf16)v.x;
    tile[c4 + 1][r] = (bf16)v.y;
    tile[c4 + 2][r] = (bf16)v.z;
    tile[c4 + 3][r] = (bf16)v.w;
  }
  __syncthreads();
  const int dr8 = t >> 3;
  const int sc8 = (t & 7) * 8;
#pragma unroll
  for (int i = 0; i < 2; ++i) {
    int dr = i * 32 + dr8;
    bf16x8 o = *(const bf16x8*)&tile[dr][sc8];
    *(bf16x8*)&Vt[((size_t)b * DD + d0 + dr) * SS + s0 + sc8] = o;
  }
}

// ---------------- K3: QK -> S (fp16) + row stats ----------------
// grid (64 qt, 8 kc, 4 b), 256 thr (4 waves). Wave w: k-rows [kc*256+w*64, +64).

__launch_bounds__(256, 4)
__global__ void stats2_kernel(const float* __restrict__ Qp, const bf16* __restrict__ Kw,
                              f16* __restrict__ Sp, float* __restrict__ stats) {
  __shared__ bf16 Qs[32 * 512];
  __shared__ float red[4][2][32];

  const int tid  = threadIdx.x;
  const int w    = tid >> 6;
  const int lane = tid & 63;
  const int l31  = lane & 31;
  const int lh8  = (lane >> 5) * 8;
  const int qt = blockIdx.x, kc = blockIdx.y, b = blockIdx.z;
  const int q0 = qt * 32;
  const int k0 = kc * 256 + w * 64;

  // stage Q tile (32 x 512) fp32 -> bf16, swizzled
  {
    const float* Qb = Qp + ((size_t)b * SS + q0) * DD;
#pragma unroll
    for (int i = 0; i < 8; ++i) {
      int f = i * 256 + tid;
      int row = f >> 6, c8 = (f & 63) * 8;
      float4 v0 = *(const float4*)&Qb[(size_t)row * DD + c8];
      float4 v1 = *(const float4*)&Qb[(size_t)row * DD + c8 + 4];
      bf16x8 h = { (bf16)v0.x, (bf16)v0.y, (bf16)v0.z, (bf16)v0.w,
                   (bf16)v1.x, (bf16)v1.y, (bf16)v1.z, (bf16)v1.w };
      *(bf16x8*)&Qs[row * 512 + (((c8 >> 3) ^ (row & 7)) << 3)] = h;
    }
  }
  __syncthreads();

  int qrow[16];
#pragma unroll
  for (int r = 0; r < 16; ++r) qrow[r] = (r & 3) + 8 * (r >> 2) + 4 * (lane >> 5);

  // QK: 2 accumulators (k-rows +0/+32), distance-4 register prefetch
  const bf16* pk0 = Kw + ((size_t)b * SS + k0 + l31) * DD + lh8;
  const bf16* pk1 = pk0 + (size_t)32 * DD;
  f32x16 acc0 = {}, acc1 = {};
  bf16x8 g0[4], g1[4];
#pragma unroll
  for (int j = 0; j < 4; ++j) {
    g0[j] = *(const bf16x8*)(pk0 + j * 16);
    g1[j] = *(const bf16x8*)(pk1 + j * 16);
  }
#pragma unroll
  for (int kk = 0; kk < 32; ++kk) {
    bf16x8 af = *(const bf16x8*)&Qs[sw(l31, kk * 16 + lh8)];
    acc0 = __builtin_amdgcn_mfma_f32_32x32x16_bf16(af, g0[kk & 3], acc0, 0, 0, 0);
    acc1 = __builtin_amdgcn_mfma_f32_32x32x16_bf16(af, g1[kk & 3], acc1, 0, 0, 0);
    if (kk < 28) {
      g0[kk & 3] = *(const bf16x8*)(pk0 + (kk + 4) * 16);
      g1[kk & 3] = *(const bf16x8*)(pk1 + (kk + 4) * 16);
    }
  }

  // write S (fp16) + per-row partial stats
  f16* Sb = Sp + ((size_t)b * SS + q0) * SS + k0;
  float sumv[16], sqv[16];
#pragma unroll
  for (int r = 0; r < 16; ++r) {
    float s0 = acc0[r] * SCALE, s1 = acc1[r] * SCALE;
    f16* Sr = Sb + (size_t)qrow[r] * SS;
    Sr[l31]      = (f16)s0;
    Sr[32 + l31] = (f16)s1;
    sumv[r] = s0 + s1;
    sqv[r]  = s0 * s0 + s1 * s1;
  }
#pragma unroll
  for (int r = 0; r < 16; ++r) {
    float v1 = sumv[r], v2 = sqv[r];
#pragma unroll
    for (int m = 16; m >= 1; m >>= 1) { v1 += __shfl_xor(v1, m); v2 += __shfl_xor(v2, m); }
    if (l31 == 0) { red[w][0][qrow[r]] = v1; red[w][1][qrow[r]] = v2; }
  }
  __syncthreads();
  if (tid < 32) {
    float s = red[0][0][tid] + red[1][0][tid] + red[2][0][tid] + red[3][0][tid];
    float q = red[0][1][tid] + red[1][1][tid] + red[2][1][tid] + red[3][1][tid];
    atomicAdd(&stats[b * SS + q0 + tid], s);
    atomicAdd(&stats[BB * SS + b * SS + q0 + tid], q);
  }
}

// ---------------- K4: softmax + PV, d-split, direct output ----------------
// grid (64 qt, 4 dsl, 4 b), 256 thr (4 waves). Wave w: d [dsl*128+w*32, +32),
// all 2048 k in four 512-k chunks. Block-local denominator. No partials.

__launch_bounds__(256, 4)
__global__ void pv2_kernel(const f16* __restrict__ Sp, const float* __restrict__ stats,
                           const bf16* __restrict__ Vt, float* __restrict__ out) {
  __shared__ bf16 Ps[32 * 512];
  __shared__ float a1s[32];
  __shared__ float dscr[32];

  const int tid  = threadIdx.x;
  const int w    = tid >> 6;
  const int lane = tid & 63;
  const int l31  = lane & 31;
  const int lh8  = (lane >> 5) * 8;
  const int qt = blockIdx.x, dsl = blockIdx.y, b = blockIdx.z;
  const int q0 = qt * 32;
  const int d0 = dsl * 128 + w * 32;

  if (tid < 32) {
    float s  = stats[b * SS + q0 + tid];
    float sq = stats[BB * SS + b * SS + q0 + tid];
    float mean = s * (1.0f / 2048.0f);
    float var  = (sq - 2048.0f * mean * mean) * (1.0f / 2047.0f);
    var = fmaxf(var, 0.0f);
    // p = exp((s-mean)*istd); exp(-mean*istd) is per-row and cancels in
    // softmax -> exponent = s * istd (log2-folded). S already carries SCALE.
    a1s[tid]  = LOG2E / (sqrtf(var) + 1e-6f);
    dscr[tid] = 0.f;
  }
  __syncthreads();

  int qrow[16];
#pragma unroll
  for (int r = 0; r < 16; ++r) qrow[r] = (r & 3) + 8 * (r >> 2) + 4 * (lane >> 5);

  const bf16* pV = Vt + ((size_t)b * DD + d0 + l31) * SS + lh8;
  const f16*  Sq = Sp + ((size_t)b * SS + q0) * SS;
  f32x16 acc = {};

  for (int kc = 0; kc < 4; ++kc) {
    if (kc) __syncthreads();   // previous chunk's PV reads of Ps are done

    // build P chunk (32 x 512): read S f16, exp2, store bf16 swizzled; den
    const f16* Sb = Sq + kc * 512;
#pragma unroll
    for (int i = 0; i < 8; ++i) {
      int f = i * 256 + tid;
      int row = f >> 6, g = f & 63;
      f16x8 hv = *(const f16x8*)&Sb[(size_t)row * SS + g * 8];
      float a1 = a1s[row];
      bf16x8 pb;
      float loc = 0.f;
#pragma unroll
      for (int j = 0; j < 8; ++j) {
        float p = exp2f((float)hv[j] * a1);
        bf16 pc = (bf16)p;
        pb[j] = pc;
        loc += (float)pc;   // denominator from the same bf16 values PV uses
      }
      *(bf16x8*)&Ps[row * 512 + ((g ^ (row & 7)) << 3)] = pb;
      atomicAdd(&dscr[row], loc);
    }
    __syncthreads();   // P chunk complete (and dscr for this chunk)

    // PV over this chunk: 1 acc, distance-8 prefetch of Vt B-fragments
    const bf16* pVc = pV + kc * 512;
    bf16x8 gv[8];
#pragma unroll
    for (int j = 0; j < 8; ++j) gv[j] = *(const bf16x8*)(pVc + j * 16);
#pragma unroll
    for (int kk = 0; kk < 32; ++kk) {
      bf16x8 pf = *(const bf16x8*)&Ps[sw(l31, kk * 16 + lh8)];
      acc = __builtin_amdgcn_mfma_f32_32x32x16_bf16(pf, gv[kk & 7], acc, 0, 0, 0);
      if (kk < 24) gv[kk & 7] = *(const bf16x8*)(pVc + (kk + 8) * 16);
    }
  }

  // dscr finalized at the kc=3 post-P-build barrier; PV loop only reads Ps.
  float* Ob = out + ((size_t)b * SS + q0) * DD + d0;
#pragma unroll
  for (int r = 0; r < 16; ++r) {
    Ob[(size_t)qrow[r] * DD + l31] = acc[r] * (1.0f / dscr[qrow[r]]);
  }
}

// ---------------- fallback (round-1 kernel, zero workspace) ----------------

#define QS_STRIDE 520
#define KS_STRIDE 72
#define VT_STRIDE 18
#define PS_STRIDE 136

__device__ __forceinline__ f32x16 qk_tile(const float* __restrict__ Kb,
                                          const bf16* __restrict__ Qsl,
                                          bf16* __restrict__ KVw,
                                          int l31, int lh8, int lane) {
  f32x16 acc = {};
  for (int dc = 0; dc < DD; dc += 64) {
#pragma unroll
    for (int i = 0; i < 8; ++i) {
      int f = i * 64 + lane;
      int row = f >> 4;
      int c4 = (f & 15) * 4;
      float4 v = *(const float4*)(Kb + row * DD + dc + c4);
      bf16x4 h = { (bf16)v.x, (bf16)v.y, (bf16)v.z, (bf16)v.w };
      *(bf16x4*)&KVw[row * KS_STRIDE + c4] = h;
    }
#pragma unroll
    for (int ks = 0; ks < 4; ++ks) {
      bf16x8 a  = *(const bf16x8*)&Qsl[l31 * QS_STRIDE + dc + ks * 16 + lh8];
      bf16x8 bb = *(const bf16x8*)&KVw[l31 * KS_STRIDE + ks * 16 + lh8];
      acc = __builtin_amdgcn_mfma_f32_32x32x16_bf16(a, bb, acc, 0, 0, 0);
    }
  }
  return acc;
}

__launch_bounds__(256, 1)
__global__ void nm_attn_kernel(const float* __restrict__ Qp,
                               const float* __restrict__ Kp,
                               const float* __restrict__ Vp,
                               float* __restrict__ Op) {
  __shared__ bf16 Qs[32 * QS_STRIDE];
  __shared__ bf16 KVu[4][32 * KS_STRIDE];
  __shared__ bf16 Psl[32 * PS_STRIDE];
  __shared__ float redA[4][32];
  __shared__ float redB[4][32];
  __shared__ float a0v[32], a1v[32], idv[32];

  const int tid  = threadIdx.x;
  const int w    = tid >> 6;
  const int lane = tid & 63;
  const int l31  = lane & 31;
  const int lh8  = (lane >> 5) * 8;
  const int b    = blockIdx.y;
  const int q0   = blockIdx.x * 32;

  {
    const float* Qbase = Qp + (size_t)(b * SS + q0) * DD;
#pragma unroll
    for (int i = 0; i < 16; ++i) {
      int f = i * 256 + tid;
      int row = f >> 7;
      int c4 = (f & 127) * 4;
      float4 v = *(const float4*)(Qbase + row * DD + c4);
      bf16x4 h = { (bf16)v.x, (bf16)v.y, (bf16)v.z, (bf16)v.w };
      *(bf16x4*)&Qs[row * QS_STRIDE + c4] = h;
    }
  }
  __syncthreads();

  int qrow[16];
#pragma unroll
  for (int r = 0; r < 16; ++r) qrow[r] = (r & 3) + 8 * (r >> 2) + 4 * (lane >> 5);

  float sumv[16], sqv[16];
#pragma unroll
  for (int r = 0; r < 16; ++r) { sumv[r] = 0.f; sqv[r] = 0.f; }

  for (int kt = 0; kt < 16; ++kt) {
    const float* Kb = Kp + (size_t)(b * SS + kt * 128 + w * 32) * DD;
    f32x16 acc = qk_tile(Kb, Qs, KVu[w], l31, lh8, lane);
#pragma unroll
    for (int r = 0; r < 16; ++r) {
      float s = acc[r] * SCALE;
      sumv[r] += s;
      sqv[r]  += s * s;
    }
  }

#pragma unroll
  for (int r = 0; r < 16; ++r) {
    float v1 = sumv[r], v2 = sqv[r];
#pragma unroll
    for (int m = 16; m >= 1; m >>= 1) {
      v1 += __shfl_xor(v1, m);
      v2 += __shfl_xor(v2, m);
    }
    if (l31 == 0) { redA[w][qrow[r]] = v1; redB[w][qrow[r]] = v2; }
  }
  __syncthreads();
  if (tid < 32) {
    float s  = redA[0][tid] + redA[1][tid] + redA[2][tid] + redA[3][tid];
    float sq = redB[0][tid] + redB[1][tid] + redB[2][tid] + redB[3][tid];
    float mean = s * (1.0f / 2048.0f);
    float var = (sq - 2048.0f * mean * mean) * (1.0f / 2047.0f);
    var = fmaxf(var, 0.0f);
    float istd = 1.0f / (sqrtf(var) + 1e-6f);
    a1v[tid] = istd * LOG2E;
    a0v[tid] = -mean * istd * LOG2E;
  }
  __syncthreads();

  float a0r[16], a1r[16], den[16];
#pragma unroll
  for (int r = 0; r < 16; ++r) {
    a0r[r] = a0v[qrow[r]];
    a1r[r] = a1v[qrow[r]];
    den[r] = 0.f;
  }

  f32x16 Oa[4] = {};

  for (int kt = 0; kt < 16; ++kt) {
    const float* Kb = Kp + (size_t)(b * SS + kt * 128 + w * 32) * DD;
    f32x16 acc = qk_tile(Kb, Qs, KVu[w], l31, lh8, lane);

    __syncthreads();
#pragma unroll
    for (int r = 0; r < 16; ++r) {
      float s = acc[r] * SCALE;
      float p = exp2f(fmaf(s, a1r[r], a0r[r]));
      den[r] += p;
      Psl[qrow[r] * PS_STRIDE + w * 32 + l31] = (bf16)p;
    }
    __syncthreads();

    const float* Vb = Vp + (size_t)(b * SS + kt * 128) * DD + w * 128 + 2 * lane;
    bf16* Vts = KVu[w];
    const int d0 = 2 * lane;
    for (int ks2 = 0; ks2 < 8; ++ks2) {
      const float* Vk = Vb + ks2 * 16 * DD;
#pragma unroll
      for (int i = 0; i < 8; ++i) {
        float2 va = *(const float2*)(Vk + (2 * i) * DD);
        float2 vc = *(const float2*)(Vk + (2 * i + 1) * DD);
        bf16x2 h0 = { (bf16)va.x, (bf16)vc.x };
        bf16x2 h1 = { (bf16)va.y, (bf16)vc.y };
        *(bf16x2*)&Vts[d0 * VT_STRIDE + 2 * i] = h0;
        *(bf16x2*)&Vts[(d0 + 1) * VT_STRIDE + 2 * i] = h1;
      }
      bf16x8 aP = *(const bf16x8*)&Psl[l31 * PS_STRIDE + ks2 * 16 + lh8];
#pragma unroll
      for (int dt = 0; dt < 4; ++dt) {
        const bf16* vr = &Vts[(dt * 32 + l31) * VT_STRIDE + lh8];
        bf16x2 e0 = *(const bf16x2*)(vr + 0);
        bf16x2 e1 = *(const bf16x2*)(vr + 2);
        bf16x2 e2 = *(const bf16x2*)(vr + 4);
        bf16x2 e3 = *(const bf16x2*)(vr + 6);
        bf16x8 bV = { e0.x, e0.y, e1.x, e1.y, e2.x, e2.y, e3.x, e3.y };
        Oa[dt] = __builtin_amdgcn_mfma_f32_32x32x16_bf16(aP, bV, Oa[dt], 0, 0, 0);
      }
    }
  }

#pragma unroll
  for (int r = 0; r < 16; ++r) {
    float v1 = den[r];
#pragma unroll
    for (int m = 16; m >= 1; m >>= 1) v1 += __shfl_xor(v1, m);
    if (l31 == 0) redA[w][qrow[r]] = v1;
  }
  __syncthreads();
  if (tid < 32) {
    float t = redA[0][tid] + redA[1][tid] + redA[2][tid] + redA[3][tid];
    idv[tid] = 1.0f / t;
  }
  __syncthreads();

  float idr[16];
#pragma unroll
  for (int r = 0; r < 16; ++r) idr[r] = idv[qrow[r]];

  float* Ob = Op + (size_t)(b * SS + q0) * DD + w * 128;
#pragma unroll
  for (int dt = 0; dt < 4; ++dt) {
#pragma unroll
    for (int r = 0; r < 16; ++r) {
      Ob[qrow[r] * DD + dt * 32 + l31] = Oa[dt][r] * idr[r];
    }
  }
}

// ---------------- launcher ----------------

extern "C" void kernel_launch(void* const* d_in, const int* in_sizes, int n_in,
                              void* d_out, int out_size, void* d_ws, size_t ws_size,
                              hipStream_t stream) {
  const float* Q = (const float*)d_in[0];
  const float* K = (const float*)d_in[1];
  const float* V = (const float*)d_in[2];
  float* out = (float*)d_out;
  (void)in_sizes; (void)n_in; (void)out_size;

  const size_t E  = (size_t)BB * SS * DD;   // 4,194,304 elems / tensor
  const size_t SE = (size_t)BB * SS * SS;   // 16,777,216 score elems

  // ws layout: [Kb bf16 E][Vt bf16 E][S f16 SE][stats 2*B*S f32]
  const size_t off_Vt    = E * sizeof(bf16);
  const size_t off_S     = off_Vt + E * sizeof(bf16);
  const size_t off_stats = off_S + SE * sizeof(f16);
  const size_t need      = off_stats + 2 * (size_t)BB * SS * sizeof(float); // ~50.4 MB

  if (ws_size >= need) {
    char* ws = (char*)d_ws;
    bf16*  Kb    = (bf16*)ws;
    bf16*  Vt    = (bf16*)(ws + off_Vt);
    f16*   Sp    = (f16*)(ws + off_S);
    float* stats = (float*)(ws + off_stats);

    hipMemsetAsync(stats, 0, 2 * (size_t)BB * SS * sizeof(float), stream);
    cast_k_kernel<<<(int)(E / 8 / 256), 256, 0, stream>>>(K, Kb);
    transpose_v_kernel<<<dim3(SS / 64, DD / 64, BB), 256, 0, stream>>>(V, Vt);
    stats2_kernel<<<dim3(SS / 32, 8, BB), 256, 0, stream>>>(Q, Kb, Sp, stats);
    pv2_kernel<<<dim3(SS / 32, 4, BB), 256, 0, stream>>>(Sp, stats, Vt, out);
  } else {
    nm_attn_kernel<<<dim3(SS / 32, BB), dim3(256, 1, 1), 0, stream>>>(Q, K, V, out);
  }
}

// Round 6
// 197.771 us; speedup vs baseline: 1.4373x; 1.4373x over previous
//
#include <hip/hip_runtime.h>

// NeuromodulatedAttention — MI355X (gfx950), round 6
//
// ALGEBRA: (1) dopamine/serotonin "mod" is a per-row constant added before the
// per-row mean/std normalization -> cancels exactly (both MLPs are dead code).
// (2) the mean subtraction is a per-row constant inside softmax -> also cancels.
// Effective:  out = softmax( S * istd_row ) @ V,
//   S = Q K^T / sqrt(512),  istd_row = 1/(std(S_row, ddof=1) + 1e-6).
//
// Round-6: both heavy phases rebuilt as m97-style GEMMs (LDS tiles staged via
// global_load_lds width-16 with XOR chunk swizzle, MFMA from LDS) — the only
// structure measured >300 TF at these shapes on this chip. P built exactly once
// by a trivial elementwise softmax pass (den exact, no atomics).
//   K1 cast_qk:  Q,K fp32 -> bf16
//   K2 transpose_v: V -> Vt bf16 [b][d][s]
//   K3 qk_gemm:  S = Q K^T * SCALE (f16) + row stats atomics. 128x128xBK64,
//                grid (16,16,4)=1024 blocks, 4 waves, 2x2 accs/wave.
//   K4 softmax:  P = bf16(exp2(S*a1)), den[row] = sum(P). 1 block/row.
//   K5 pv_gemm:  out = (P @ V) / den. 128qx64dxBK64, grid (16,8,4)=512 blocks.

#define BB 4
#define SS 2048
#define DD 512
#define SCALE 0.044194173824159216f  // 1/sqrt(512)
#define LOG2E 1.4426950408889634f

typedef __bf16 bf16;
typedef _Float16 f16;
typedef bf16 bf16x2 __attribute__((ext_vector_type(2)));
typedef bf16 bf16x4 __attribute__((ext_vector_type(4)));
typedef bf16 bf16x8 __attribute__((ext_vector_type(8)));
typedef f16  f16x8  __attribute__((ext_vector_type(8)));
typedef float f32x16 __attribute__((ext_vector_type(16)));

// async 16B/lane global->LDS. LDS side scatters base + lane*16 (wave-uniform
// base); global side is per-lane.
__device__ __forceinline__ void gload_lds16(const bf16* g, bf16* l) {
  __builtin_amdgcn_global_load_lds(
      (const __attribute__((address_space(1))) void*)g,
      (__attribute__((address_space(3))) void*)l, 16, 0, 0);
}

// ---------------- K1: cast Q,K to bf16 ----------------

__global__ void cast_qk_kernel(const float* __restrict__ Q, const float* __restrict__ K,
                               bf16* __restrict__ Qb, bf16* __restrict__ Kb) {
  size_t i = ((size_t)blockIdx.x * 256 + threadIdx.x) * 8;
  float4 a0 = *(const float4*)(Q + i);
  float4 a1 = *(const float4*)(Q + i + 4);
  bf16x8 qa = { (bf16)a0.x, (bf16)a0.y, (bf16)a0.z, (bf16)a0.w,
                (bf16)a1.x, (bf16)a1.y, (bf16)a1.z, (bf16)a1.w };
  *(bf16x8*)(Qb + i) = qa;
  float4 b0 = *(const float4*)(K + i);
  float4 b1 = *(const float4*)(K + i + 4);
  bf16x8 ka = { (bf16)b0.x, (bf16)b0.y, (bf16)b0.z, (bf16)b0.w,
                (bf16)b1.x, (bf16)b1.y, (bf16)b1.z, (bf16)b1.w };
  *(bf16x8*)(Kb + i) = ka;
}

// ---------------- K2: V [b][s][d] fp32 -> Vt [b][d][s] bf16 ----------------

__global__ void transpose_v_kernel(const float* __restrict__ V, bf16* __restrict__ Vt) {
  __shared__ bf16 tile[64][80];
  const int b = blockIdx.z;
  const int s0 = blockIdx.x * 64, d0 = blockIdx.y * 64;
  const int t = threadIdx.x;
  const int r16 = t >> 4;
  const int c4  = (t & 15) * 4;
#pragma unroll
  for (int i = 0; i < 4; ++i) {
    int r = i * 16 + r16;
    float4 v = *(const float4*)&V[((size_t)b * SS + s0 + r) * DD + d0 + c4];
    tile[c4 + 0][r] = (bf16)v.x;
    tile[c4 + 1][r] = (bf16)v.y;
    tile[c4 + 2][r] = (bf16)v.z;
    tile[c4 + 3][r] = (bf16)v.w;
  }
  __syncthreads();
  const int dr8 = t >> 3;
  const int sc8 = (t & 7) * 8;
#pragma unroll
  for (int i = 0; i < 2; ++i) {
    int dr = i * 32 + dr8;
    bf16x8 o = *(const bf16x8*)&tile[dr][sc8];
    *(bf16x8*)&Vt[((size_t)b * DD + d0 + dr) * SS + s0 + sc8] = o;
  }
}

// ---------------- K3: QK^T GEMM -> S f16 + stats ----------------
// grid (16 qt, 16 kt, 4 b), 256 thr (4 waves). Tile 128q x 128k, BK=64 (8 iters).
// Wave (wq=w&1, wn=w>>1) owns the 64x64 quadrant (m0=wq*64, n0=wn*64).
// LDS tiles [128][64] bf16, rows contiguous 128B; chunk slot s of row r holds
// global chunk s^(r&7) (staged that way; reads XOR back) to spread banks.

__launch_bounds__(256, 2)
__global__ void qk_gemm_kernel(const bf16* __restrict__ Qb, const bf16* __restrict__ Kb,
                               f16* __restrict__ Sp, float* __restrict__ stats) {
  __shared__ bf16 At[128 * 64];
  __shared__ bf16 Bt[128 * 64];
  __shared__ float redS[2][128];
  __shared__ float redQ[2][128];

  const int tid  = threadIdx.x;
  const int w    = tid >> 6;
  const int lane = tid & 63;
  const int l31  = lane & 31;
  const int lh   = lane >> 5;
  const int qt = blockIdx.x, kt = blockIdx.y, b = blockIdx.z;
  const int q0 = qt * 128, k0 = kt * 128;
  const int wq = w & 1, wn = w >> 1;
  const int m0 = wq * 64, n0 = wn * 64;

  const int srow = lane >> 3;          // 0..7 row within 8-row staging group
  const int sg   = (lane & 7) ^ srow;  // swizzled global chunk index
  const bf16* gA = Qb + ((size_t)b * SS + q0) * DD;
  const bf16* gB = Kb + ((size_t)b * SS + k0) * DD;

  f32x16 acc00 = {}, acc01 = {}, acc10 = {}, acc11 = {};

  for (int dc = 0; dc < DD; dc += 64) {
    __syncthreads();
#pragma unroll
    for (int j = 0; j < 4; ++j) {
      int row = w * 32 + j * 8 + srow;
      gload_lds16(gA + (size_t)row * DD + dc + sg * 8, At + (w * 32 + j * 8) * 64);
      gload_lds16(gB + (size_t)row * DD + dc + sg * 8, Bt + (w * 32 + j * 8) * 64);
    }
    __syncthreads();
#pragma unroll
    for (int kk = 0; kk < 4; ++kk) {
      int c = kk * 2 + lh;
      int ra0 = m0 + l31, ra1 = m0 + 32 + l31;
      int rb0 = n0 + l31, rb1 = n0 + 32 + l31;
      bf16x8 a0 = *(const bf16x8*)&At[ra0 * 64 + ((c ^ (ra0 & 7)) << 3)];
      bf16x8 a1 = *(const bf16x8*)&At[ra1 * 64 + ((c ^ (ra1 & 7)) << 3)];
      bf16x8 b0 = *(const bf16x8*)&Bt[rb0 * 64 + ((c ^ (rb0 & 7)) << 3)];
      bf16x8 b1 = *(const bf16x8*)&Bt[rb1 * 64 + ((c ^ (rb1 & 7)) << 3)];
      acc00 = __builtin_amdgcn_mfma_f32_32x32x16_bf16(a0, b0, acc00, 0, 0, 0);
      acc01 = __builtin_amdgcn_mfma_f32_32x32x16_bf16(a0, b1, acc01, 0, 0, 0);
      acc10 = __builtin_amdgcn_mfma_f32_32x32x16_bf16(a1, b0, acc10, 0, 0, 0);
      acc11 = __builtin_amdgcn_mfma_f32_32x32x16_bf16(a1, b1, acc11, 0, 0, 0);
    }
  }

  int qrow[16];
#pragma unroll
  for (int r = 0; r < 16; ++r) qrow[r] = (r & 3) + 8 * (r >> 2) + 4 * lh;

  // epilogue: write S f16 + per-row (sum, sumsq) partials for this 128-col block
  f16* Sb = Sp + ((size_t)b * SS + q0) * SS + k0 + n0;
#pragma unroll
  for (int i = 0; i < 2; ++i) {
    const f32x16& A0 = i ? acc10 : acc00;
    const f32x16& A1 = i ? acc11 : acc01;
#pragma unroll
    for (int r = 0; r < 16; ++r) {
      float s0 = A0[r] * SCALE, s1 = A1[r] * SCALE;
      f16* Sr = Sb + (size_t)(m0 + i * 32 + qrow[r]) * SS;
      Sr[l31]      = (f16)s0;
      Sr[32 + l31] = (f16)s1;
      float sv = s0 + s1;
      float qv = s0 * s0 + s1 * s1;
#pragma unroll
      for (int m = 16; m >= 1; m >>= 1) { sv += __shfl_xor(sv, m); qv += __shfl_xor(qv, m); }
      if (l31 == 0) {
        redS[wn][m0 + i * 32 + qrow[r]] = sv;
        redQ[wn][m0 + i * 32 + qrow[r]] = qv;
      }
    }
  }
  __syncthreads();
  if (tid < 128) {
    atomicAdd(&stats[b * SS + q0 + tid], redS[0][tid] + redS[1][tid]);
    atomicAdd(&stats[BB * SS + b * SS + q0 + tid], redQ[0][tid] + redQ[1][tid]);
  }
}

// ---------------- K4: softmax S f16 -> P bf16 + exact den ----------------
// grid (2048, 4), 256 thr; block = one q-row (2048 elems, 8/thread).

__global__ void softmax_kernel(const f16* __restrict__ Sp, const float* __restrict__ stats,
                               bf16* __restrict__ Pp, float* __restrict__ den) {
  __shared__ float ws4[4];
  const int row = blockIdx.x, b = blockIdx.y;
  const int tid = threadIdx.x;
  const size_t base = ((size_t)b * SS + row) * SS;

  float s  = stats[b * SS + row];
  float sq = stats[BB * SS + b * SS + row];
  float mean = s * (1.0f / 2048.0f);
  float var  = (sq - 2048.0f * mean * mean) * (1.0f / 2047.0f);
  var = fmaxf(var, 0.0f);
  // p = exp((s-mean)*istd); per-row exp(-mean*istd) cancels in softmax.
  float a1 = LOG2E / (sqrtf(var) + 1e-6f);

  f16x8 hv = *(const f16x8*)&Sp[base + tid * 8];
  bf16x8 pb;
  float loc = 0.f;
#pragma unroll
  for (int j = 0; j < 8; ++j) {
    float p = exp2f((float)hv[j] * a1);
    bf16 pc = (bf16)p;
    pb[j] = pc;
    loc += (float)pc;   // denominator from the same bf16 values PV uses
  }
  *(bf16x8*)&Pp[base + tid * 8] = pb;

#pragma unroll
  for (int m = 32; m >= 1; m >>= 1) loc += __shfl_xor(loc, m);
  if ((tid & 63) == 0) ws4[tid >> 6] = loc;
  __syncthreads();
  if (tid == 0) den[b * SS + row] = ws4[0] + ws4[1] + ws4[2] + ws4[3];
}

// ---------------- K5: PV GEMM -> out (fp32), / den ----------------
// grid (16 qt, 8 dt, 4 b), 256 thr (4 waves). Tile 128q x 64d, BK=64 (32 iters).
// Wave w owns rows [w*32, +32), cols 64 (2 accs). A = P [q][s], B = Vt [d][s].

__launch_bounds__(256, 4)
__global__ void pv_gemm_kernel(const bf16* __restrict__ Pp, const bf16* __restrict__ Vt,
                               const float* __restrict__ den, float* __restrict__ out) {
  __shared__ bf16 At[128 * 64];
  __shared__ bf16 Bt[64 * 64];
  __shared__ float dinv[128];

  const int tid  = threadIdx.x;
  const int w    = tid >> 6;
  const int lane = tid & 63;
  const int l31  = lane & 31;
  const int lh   = lane >> 5;
  const int qt = blockIdx.x, dt = blockIdx.y, b = blockIdx.z;
  const int q0 = qt * 128, d0 = dt * 64;

  if (tid < 128) dinv[tid] = 1.0f / den[b * SS + q0 + tid];

  const int srow = lane >> 3;
  const int sg   = (lane & 7) ^ srow;
  const bf16* gA = Pp + ((size_t)b * SS + q0) * SS;
  const bf16* gB = Vt + ((size_t)b * DD + d0) * SS;

  f32x16 acc0 = {}, acc1 = {};

  for (int kc = 0; kc < SS; kc += 64) {
    __syncthreads();
#pragma unroll
    for (int j = 0; j < 4; ++j) {
      int row = w * 32 + j * 8 + srow;
      gload_lds16(gA + (size_t)row * SS + kc + sg * 8, At + (w * 32 + j * 8) * 64);
    }
#pragma unroll
    for (int j = 0; j < 2; ++j) {
      int row = w * 16 + j * 8 + srow;
      gload_lds16(gB + (size_t)row * SS + kc + sg * 8, Bt + (w * 16 + j * 8) * 64);
    }
    __syncthreads();
#pragma unroll
    for (int kk = 0; kk < 4; ++kk) {
      int c = kk * 2 + lh;
      int ra = w * 32 + l31;
      int rb0 = l31, rb1 = 32 + l31;
      bf16x8 af = *(const bf16x8*)&At[ra * 64 + ((c ^ (ra & 7)) << 3)];
      bf16x8 b0 = *(const bf16x8*)&Bt[rb0 * 64 + ((c ^ (rb0 & 7)) << 3)];
      bf16x8 b1 = *(const bf16x8*)&Bt[rb1 * 64 + ((c ^ (rb1 & 7)) << 3)];
      acc0 = __builtin_amdgcn_mfma_f32_32x32x16_bf16(af, b0, acc0, 0, 0, 0);
      acc1 = __builtin_amdgcn_mfma_f32_32x32x16_bf16(af, b1, acc1, 0, 0, 0);
    }
  }

  int qrow[16];
#pragma unroll
  for (int r = 0; r < 16; ++r) qrow[r] = (r & 3) + 8 * (r >> 2) + 4 * lh;

  float* Ob = out + ((size_t)b * SS + q0) * DD + d0;
#pragma unroll
  for (int r = 0; r < 16; ++r) {
    int row = w * 32 + qrow[r];
    float iv = dinv[row];
    float* Or = Ob + (size_t)row * DD;
    Or[l31]      = acc0[r] * iv;
    Or[32 + l31] = acc1[r] * iv;
  }
}

// ---------------- fallback (round-1 kernel, zero workspace) ----------------

#define QS_STRIDE 520
#define KS_STRIDE 72
#define VT_STRIDE 18
#define PS_STRIDE 136

__device__ __forceinline__ f32x16 qk_tile(const float* __restrict__ Kb,
                                          const bf16* __restrict__ Qsl,
                                          bf16* __restrict__ KVw,
                                          int l31, int lh8, int lane) {
  f32x16 acc = {};
  for (int dc = 0; dc < DD; dc += 64) {
#pragma unroll
    for (int i = 0; i < 8; ++i) {
      int f = i * 64 + lane;
      int row = f >> 4;
      int c4 = (f & 15) * 4;
      float4 v = *(const float4*)(Kb + row * DD + dc + c4);
      bf16x4 h = { (bf16)v.x, (bf16)v.y, (bf16)v.z, (bf16)v.w };
      *(bf16x4*)&KVw[row * KS_STRIDE + c4] = h;
    }
#pragma unroll
    for (int ks = 0; ks < 4; ++ks) {
      bf16x8 a  = *(const bf16x8*)&Qsl[l31 * QS_STRIDE + dc + ks * 16 + lh8];
      bf16x8 bb = *(const bf16x8*)&KVw[l31 * KS_STRIDE + ks * 16 + lh8];
      acc = __builtin_amdgcn_mfma_f32_32x32x16_bf16(a, bb, acc, 0, 0, 0);
    }
  }
  return acc;
}

__launch_bounds__(256, 1)
__global__ void nm_attn_kernel(const float* __restrict__ Qp,
                               const float* __restrict__ Kp,
                               const float* __restrict__ Vp,
                               float* __restrict__ Op) {
  __shared__ bf16 Qs[32 * QS_STRIDE];
  __shared__ bf16 KVu[4][32 * KS_STRIDE];
  __shared__ bf16 Psl[32 * PS_STRIDE];
  __shared__ float redA[4][32];
  __shared__ float redB[4][32];
  __shared__ float a0v[32], a1v[32], idv[32];

  const int tid  = threadIdx.x;
  const int w    = tid >> 6;
  const int lane = tid & 63;
  const int l31  = lane & 31;
  const int lh8  = (lane >> 5) * 8;
  const int b    = blockIdx.y;
  const int q0   = blockIdx.x * 32;

  {
    const float* Qbase = Qp + (size_t)(b * SS + q0) * DD;
#pragma unroll
    for (int i = 0; i < 16; ++i) {
      int f = i * 256 + tid;
      int row = f >> 7;
      int c4 = (f & 127) * 4;
      float4 v = *(const float4*)(Qbase + row * DD + c4);
      bf16x4 h = { (bf16)v.x, (bf16)v.y, (bf16)v.z, (bf16)v.w };
      *(bf16x4*)&Qs[row * QS_STRIDE + c4] = h;
    }
  }
  __syncthreads();

  int qrow[16];
#pragma unroll
  for (int r = 0; r < 16; ++r) qrow[r] = (r & 3) + 8 * (r >> 2) + 4 * (lane >> 5);

  float sumv[16], sqv[16];
#pragma unroll
  for (int r = 0; r < 16; ++r) { sumv[r] = 0.f; sqv[r] = 0.f; }

  for (int kt = 0; kt < 16; ++kt) {
    const float* Kb = Kp + (size_t)(b * SS + kt * 128 + w * 32) * DD;
    f32x16 acc = qk_tile(Kb, Qs, KVu[w], l31, lh8, lane);
#pragma unroll
    for (int r = 0; r < 16; ++r) {
      float s = acc[r] * SCALE;
      sumv[r] += s;
      sqv[r]  += s * s;
    }
  }

#pragma unroll
  for (int r = 0; r < 16; ++r) {
    float v1 = sumv[r], v2 = sqv[r];
#pragma unroll
    for (int m = 16; m >= 1; m >>= 1) {
      v1 += __shfl_xor(v1, m);
      v2 += __shfl_xor(v2, m);
    }
    if (l31 == 0) { redA[w][qrow[r]] = v1; redB[w][qrow[r]] = v2; }
  }
  __syncthreads();
  if (tid < 32) {
    float s  = redA[0][tid] + redA[1][tid] + redA[2][tid] + redA[3][tid];
    float sq = redB[0][tid] + redB[1][tid] + redB[2][tid] + redB[3][tid];
    float mean = s * (1.0f / 2048.0f);
    float var = (sq - 2048.0f * mean * mean) * (1.0f / 2047.0f);
    var = fmaxf(var, 0.0f);
    float istd = 1.0f / (sqrtf(var) + 1e-6f);
    a1v[tid] = istd * LOG2E;
    a0v[tid] = -mean * istd * LOG2E;
  }
  __syncthreads();

  float a0r[16], a1r[16], den[16];
#pragma unroll
  for (int r = 0; r < 16; ++r) {
    a0r[r] = a0v[qrow[r]];
    a1r[r] = a1v[qrow[r]];
    den[r] = 0.f;
  }

  f32x16 Oa[4] = {};

  for (int kt = 0; kt < 16; ++kt) {
    const float* Kb = Kp + (size_t)(b * SS + kt * 128 + w * 32) * DD;
    f32x16 acc = qk_tile(Kb, Qs, KVu[w], l31, lh8, lane);

    __syncthreads();
#pragma unroll
    for (int r = 0; r < 16; ++r) {
      float s = acc[r] * SCALE;
      float p = exp2f(fmaf(s, a1r[r], a0r[r]));
      den[r] += p;
      Psl[qrow[r] * PS_STRIDE + w * 32 + l31] = (bf16)p;
    }
    __syncthreads();

    const float* Vb = Vp + (size_t)(b * SS + kt * 128) * DD + w * 128 + 2 * lane;
    bf16* Vts = KVu[w];
    const int d0 = 2 * lane;
    for (int ks2 = 0; ks2 < 8; ++ks2) {
      const float* Vk = Vb + ks2 * 16 * DD;
#pragma unroll
      for (int i = 0; i < 8; ++i) {
        float2 va = *(const float2*)(Vk + (2 * i) * DD);
        float2 vc = *(const float2*)(Vk + (2 * i + 1) * DD);
        bf16x2 h0 = { (bf16)va.x, (bf16)vc.x };
        bf16x2 h1 = { (bf16)va.y, (bf16)vc.y };
        *(bf16x2*)&Vts[d0 * VT_STRIDE + 2 * i] = h0;
        *(bf16x2*)&Vts[(d0 + 1) * VT_STRIDE + 2 * i] = h1;
      }
      bf16x8 aP = *(const bf16x8*)&Psl[l31 * PS_STRIDE + ks2 * 16 + lh8];
#pragma unroll
      for (int dt = 0; dt < 4; ++dt) {
        const bf16* vr = &Vts[(dt * 32 + l31) * VT_STRIDE + lh8];
        bf16x2 e0 = *(const bf16x2*)(vr + 0);
        bf16x2 e1 = *(const bf16x2*)(vr + 2);
        bf16x2 e2 = *(const bf16x2*)(vr + 4);
        bf16x2 e3 = *(const bf16x2*)(vr + 6);
        bf16x8 bV = { e0.x, e0.y, e1.x, e1.y, e2.x, e2.y, e3.x, e3.y };
        Oa[dt] = __builtin_amdgcn_mfma_f32_32x32x16_bf16(aP, bV, Oa[dt], 0, 0, 0);
      }
    }
  }

#pragma unroll
  for (int r = 0; r < 16; ++r) {
    float v1 = den[r];
#pragma unroll
    for (int m = 16; m >= 1; m >>= 1) v1 += __shfl_xor(v1, m);
    if (l31 == 0) redA[w][qrow[r]] = v1;
  }
  __syncthreads();
  if (tid < 32) {
    float t = redA[0][tid] + redA[1][tid] + redA[2][tid] + redA[3][tid];
    idv[tid] = 1.0f / t;
  }
  __syncthreads();

  float idr[16];
#pragma unroll
  for (int r = 0; r < 16; ++r) idr[r] = idv[qrow[r]];

  float* Ob = Op + (size_t)(b * SS + q0) * DD + w * 128;
#pragma unroll
  for (int dt = 0; dt < 4; ++dt) {
#pragma unroll
    for (int r = 0; r < 16; ++r) {
      Ob[qrow[r] * DD + dt * 32 + l31] = Oa[dt][r] * idr[r];
    }
  }
}

// ---------------- launcher ----------------

extern "C" void kernel_launch(void* const* d_in, const int* in_sizes, int n_in,
                              void* d_out, int out_size, void* d_ws, size_t ws_size,
                              hipStream_t stream) {
  const float* Q = (const float*)d_in[0];
  const float* K = (const float*)d_in[1];
  const float* V = (const float*)d_in[2];
  float* out = (float*)d_out;
  (void)in_sizes; (void)n_in; (void)out_size;

  const size_t E  = (size_t)BB * SS * DD;   // 4,194,304 elems / tensor
  const size_t SE = (size_t)BB * SS * SS;   // 16,777,216 score elems

  // ws layout: [Qb bf16 E][Kb bf16 E][Vt bf16 E][S f16 SE][P bf16 SE]
  //            [stats 2*B*S f32][den B*S f32]
  const size_t off_Kb    = E * sizeof(bf16);
  const size_t off_Vt    = off_Kb + E * sizeof(bf16);
  const size_t off_S     = off_Vt + E * sizeof(bf16);
  const size_t off_P     = off_S + SE * sizeof(f16);
  const size_t off_stats = off_P + SE * sizeof(bf16);
  const size_t off_den   = off_stats + 2 * (size_t)BB * SS * sizeof(float);
  const size_t need      = off_den + (size_t)BB * SS * sizeof(float);  // ~92.4 MB

  if (ws_size >= need) {
    char* ws = (char*)d_ws;
    bf16*  Qb    = (bf16*)ws;
    bf16*  Kb    = (bf16*)(ws + off_Kb);
    bf16*  Vt    = (bf16*)(ws + off_Vt);
    f16*   Sp    = (f16*)(ws + off_S);
    bf16*  Pp    = (bf16*)(ws + off_P);
    float* stats = (float*)(ws + off_stats);
    float* den   = (float*)(ws + off_den);

    hipMemsetAsync(stats, 0, 2 * (size_t)BB * SS * sizeof(float), stream);
    cast_qk_kernel<<<(int)(E / 8 / 256), 256, 0, stream>>>(Q, K, Qb, Kb);
    transpose_v_kernel<<<dim3(SS / 64, DD / 64, BB), 256, 0, stream>>>(V, Vt);
    qk_gemm_kernel<<<dim3(SS / 128, SS / 128, BB), 256, 0, stream>>>(Qb, Kb, Sp, stats);
    softmax_kernel<<<dim3(SS, BB), 256, 0, stream>>>(Sp, stats, Pp, den);
    pv_gemm_kernel<<<dim3(SS / 128, DD / 64, BB), 256, 0, stream>>>(Pp, Vt, den, out);
  } else {
    nm_attn_kernel<<<dim3(SS / 32, BB), dim3(256, 1, 1), 0, stream>>>(Q, K, V, out);
  }
}

// Round 7
// 175.692 us; speedup vs baseline: 1.6179x; 1.1257x over previous
//
#include <hip/hip_runtime.h>

// NeuromodulatedAttention — MI355X (gfx950), round 7
//
// ALGEBRA: (1) dopamine/serotonin "mod" is a per-row constant added before the
// per-row mean/std normalization -> cancels exactly (both MLPs are dead code).
// (2) the mean subtraction is a per-row constant inside softmax -> also cancels.
// Effective:  out = softmax( S * istd_row ) @ V,
//   S = Q K^T / sqrt(512),  istd_row = 1/(std(S_row, ddof=1) + 1e-6).
//
// Round-7 deltas vs round 6 (qk 44us at self-capped 2 blocks/CU; 6 dispatches):
//   * qk_gemm: launch_bounds(256,3) [LDS 32.8KB fits 4; VGPR-limited ~3] and
//     stats-free epilogue (pure f16 stores). Stats moved to softmax, which holds
//     each full row in registers anyway -> no atomics, no memset dispatch.
//   * softmax: register-resident two-phase (sum/sumsq block-reduce -> a1 ->
//     exp2 -> den block-reduce). Exact, no extra global traffic.
//   * pv_gemm: BK=128 (16 K-iters, half the barriers; grid-limited 2 blocks/CU
//     so the bigger LDS footprint costs nothing).
//   * prep: cast_qk + transpose_v fused into one dispatch (block-uniform role).

#define BB 4
#define SS 2048
#define DD 512
#define SCALE 0.044194173824159216f  // 1/sqrt(512)
#define LOG2E 1.4426950408889634f

typedef __bf16 bf16;
typedef _Float16 f16;
typedef bf16 bf16x2 __attribute__((ext_vector_type(2)));
typedef bf16 bf16x4 __attribute__((ext_vector_type(4)));
typedef bf16 bf16x8 __attribute__((ext_vector_type(8)));
typedef f16  f16x8  __attribute__((ext_vector_type(8)));
typedef float f32x16 __attribute__((ext_vector_type(16)));

// async 16B/lane global->LDS; LDS dest = wave-uniform base + lane*16.
__device__ __forceinline__ void gload_lds16(const bf16* g, bf16* l) {
  __builtin_amdgcn_global_load_lds(
      (const __attribute__((address_space(1))) void*)g,
      (__attribute__((address_space(3))) void*)l, 16, 0, 0);
}

// ---------------- K1: prep = cast Q,K (bf16) + transpose V (bf16 [b][d][s]) ----

__global__ void prep_kernel(const float* __restrict__ Q, const float* __restrict__ K,
                            const float* __restrict__ V,
                            bf16* __restrict__ Qb, bf16* __restrict__ Kb,
                            bf16* __restrict__ Vt) {
  __shared__ bf16 tile[64][80];
  const int bx = blockIdx.x;
  const int t = threadIdx.x;
  if (bx < 2048) {
    // cast 8 elems of Q and K per thread
    size_t i = ((size_t)bx * 256 + t) * 8;
    float4 a0 = *(const float4*)(Q + i);
    float4 a1 = *(const float4*)(Q + i + 4);
    bf16x8 qa = { (bf16)a0.x, (bf16)a0.y, (bf16)a0.z, (bf16)a0.w,
                  (bf16)a1.x, (bf16)a1.y, (bf16)a1.z, (bf16)a1.w };
    *(bf16x8*)(Qb + i) = qa;
    float4 b0 = *(const float4*)(K + i);
    float4 b1 = *(const float4*)(K + i + 4);
    bf16x8 ka = { (bf16)b0.x, (bf16)b0.y, (bf16)b0.z, (bf16)b0.w,
                  (bf16)b1.x, (bf16)b1.y, (bf16)b1.z, (bf16)b1.w };
    *(bf16x8*)(Kb + i) = ka;
  } else {
    // V transpose, 64x64 tile
    const int tt = bx - 2048;
    const int s0 = (tt & 31) * 64, d0 = ((tt >> 5) & 7) * 64, b = tt >> 8;
    const int r16 = t >> 4;
    const int c4  = (t & 15) * 4;
#pragma unroll
    for (int i = 0; i < 4; ++i) {
      int r = i * 16 + r16;
      float4 v = *(const float4*)&V[((size_t)b * SS + s0 + r) * DD + d0 + c4];
      tile[c4 + 0][r] = (bf16)v.x;
      tile[c4 + 1][r] = (bf16)v.y;
      tile[c4 + 2][r] = (bf16)v.z;
      tile[c4 + 3][r] = (bf16)v.w;
    }
    __syncthreads();
    const int dr8 = t >> 3;
    const int sc8 = (t & 7) * 8;
#pragma unroll
    for (int i = 0; i < 2; ++i) {
      int dr = i * 32 + dr8;
      bf16x8 o = *(const bf16x8*)&tile[dr][sc8];
      *(bf16x8*)&Vt[((size_t)b * DD + d0 + dr) * SS + s0 + sc8] = o;
    }
  }
}

// ---------------- K2: QK^T GEMM -> S f16 ----------------
// grid (16 qt, 16 kt, 4 b), 256 thr (4 waves). Tile 128q x 128k, BK=64 (8 iters).
// Wave (wq=w&1, wn=w>>1) owns the 64x64 quadrant. LDS rows 128B, chunk slot s of
// row r holds global chunk s^(r&7).

__launch_bounds__(256, 3)
__global__ void qk_gemm_kernel(const bf16* __restrict__ Qb, const bf16* __restrict__ Kb,
                               f16* __restrict__ Sp) {
  __shared__ bf16 At[128 * 64];
  __shared__ bf16 Bt[128 * 64];

  const int tid  = threadIdx.x;
  const int w    = tid >> 6;
  const int lane = tid & 63;
  const int l31  = lane & 31;
  const int lh   = lane >> 5;
  const int qt = blockIdx.x, kt = blockIdx.y, b = blockIdx.z;
  const int q0 = qt * 128, k0 = kt * 128;
  const int wq = w & 1, wn = w >> 1;
  const int m0 = wq * 64, n0 = wn * 64;

  const int srow = lane >> 3;          // row within 8-row staging group
  const int sg   = (lane & 7) ^ srow;  // swizzled global chunk index
  const bf16* gA = Qb + ((size_t)b * SS + q0) * DD;
  const bf16* gB = Kb + ((size_t)b * SS + k0) * DD;

  f32x16 acc00 = {}, acc01 = {}, acc10 = {}, acc11 = {};

  for (int dc = 0; dc < DD; dc += 64) {
    __syncthreads();
#pragma unroll
    for (int j = 0; j < 4; ++j) {
      int row = w * 32 + j * 8 + srow;
      gload_lds16(gA + (size_t)row * DD + dc + sg * 8, At + (w * 32 + j * 8) * 64);
      gload_lds16(gB + (size_t)row * DD + dc + sg * 8, Bt + (w * 32 + j * 8) * 64);
    }
    __syncthreads();
#pragma unroll
    for (int kk = 0; kk < 4; ++kk) {
      int c = kk * 2 + lh;
      int ra0 = m0 + l31, ra1 = m0 + 32 + l31;
      int rb0 = n0 + l31, rb1 = n0 + 32 + l31;
      bf16x8 a0 = *(const bf16x8*)&At[ra0 * 64 + ((c ^ (ra0 & 7)) << 3)];
      bf16x8 a1 = *(const bf16x8*)&At[ra1 * 64 + ((c ^ (ra1 & 7)) << 3)];
      bf16x8 b0 = *(const bf16x8*)&Bt[rb0 * 64 + ((c ^ (rb0 & 7)) << 3)];
      bf16x8 b1 = *(const bf16x8*)&Bt[rb1 * 64 + ((c ^ (rb1 & 7)) << 3)];
      acc00 = __builtin_amdgcn_mfma_f32_32x32x16_bf16(a0, b0, acc00, 0, 0, 0);
      acc01 = __builtin_amdgcn_mfma_f32_32x32x16_bf16(a0, b1, acc01, 0, 0, 0);
      acc10 = __builtin_amdgcn_mfma_f32_32x32x16_bf16(a1, b0, acc10, 0, 0, 0);
      acc11 = __builtin_amdgcn_mfma_f32_32x32x16_bf16(a1, b1, acc11, 0, 0, 0);
    }
  }

  int qrow[16];
#pragma unroll
  for (int r = 0; r < 16; ++r) qrow[r] = (r & 3) + 8 * (r >> 2) + 4 * lh;

  // epilogue: pure f16 stores (stats are computed in softmax from S)
  f16* Sb = Sp + ((size_t)b * SS + q0) * SS + k0 + n0;
#pragma unroll
  for (int i = 0; i < 2; ++i) {
    const f32x16& A0 = i ? acc10 : acc00;
    const f32x16& A1 = i ? acc11 : acc01;
#pragma unroll
    for (int r = 0; r < 16; ++r) {
      f16* Sr = Sb + (size_t)(m0 + i * 32 + qrow[r]) * SS;
      Sr[l31]      = (f16)(A0[r] * SCALE);
      Sr[32 + l31] = (f16)(A1[r] * SCALE);
    }
  }
}

// ---------------- K3: softmax (stats + P + den), register-resident ----------------
// grid (2048, 4), 256 thr; block = one q-row (2048 f16, 8/thread, kept in regs).

__global__ void softmax_kernel(const f16* __restrict__ Sp, bf16* __restrict__ Pp,
                               float* __restrict__ den) {
  __shared__ float redS[4], redQ[4], redD[4];
  const int row = blockIdx.x, b = blockIdx.y;
  const int tid = threadIdx.x;
  const int lane = tid & 63, w = tid >> 6;
  const size_t base = ((size_t)b * SS + row) * SS;

  f16x8 hv = *(const f16x8*)&Sp[base + tid * 8];
  float v[8];
  float s = 0.f, q = 0.f;
#pragma unroll
  for (int j = 0; j < 8; ++j) {
    v[j] = (float)hv[j];
    s += v[j];
    q += v[j] * v[j];
  }
#pragma unroll
  for (int m = 32; m >= 1; m >>= 1) { s += __shfl_xor(s, m); q += __shfl_xor(q, m); }
  if (lane == 0) { redS[w] = s; redQ[w] = q; }
  __syncthreads();
  s = redS[0] + redS[1] + redS[2] + redS[3];
  q = redQ[0] + redQ[1] + redQ[2] + redQ[3];
  float mean = s * (1.0f / 2048.0f);
  float var  = (q - 2048.0f * mean * mean) * (1.0f / 2047.0f);
  var = fmaxf(var, 0.0f);
  // p = exp((s-mean)*istd); per-row exp(-mean*istd) cancels in softmax.
  float a1 = LOG2E / (sqrtf(var) + 1e-6f);

  bf16x8 pb;
  float loc = 0.f;
#pragma unroll
  for (int j = 0; j < 8; ++j) {
    float p = exp2f(v[j] * a1);
    bf16 pc = (bf16)p;
    pb[j] = pc;
    loc += (float)pc;   // denominator from the same bf16 values PV uses
  }
  *(bf16x8*)&Pp[base + tid * 8] = pb;

#pragma unroll
  for (int m = 32; m >= 1; m >>= 1) loc += __shfl_xor(loc, m);
  if (lane == 0) redD[w] = loc;
  __syncthreads();
  if (tid == 0) den[b * SS + row] = redD[0] + redD[1] + redD[2] + redD[3];
}

// ---------------- K4: PV GEMM -> out (fp32), / den ----------------
// grid (16 qt, 8 dt, 4 b), 256 thr (4 waves). Tile 128q x 64d, BK=128 (16 iters).
// LDS rows 256B (16 chunks of 16B); chunk slot s of row r holds global chunk
// s^(r&7). Wave w owns rows [w*32,+32), all 64 cols (2 accs).

__launch_bounds__(256, 2)
__global__ void pv_gemm_kernel(const bf16* __restrict__ Pp, const bf16* __restrict__ Vt,
                               const float* __restrict__ den, float* __restrict__ out) {
  __shared__ bf16 At[128 * 128];   // 32 KB
  __shared__ bf16 Bt[64 * 128];    // 16 KB
  __shared__ float dinv[128];

  const int tid  = threadIdx.x;
  const int w    = tid >> 6;
  const int lane = tid & 63;
  const int l31  = lane & 31;
  const int lh   = lane >> 5;
  const int qt = blockIdx.x, dt = blockIdx.y, b = blockIdx.z;
  const int q0 = qt * 128, d0 = dt * 64;

  if (tid < 128) dinv[tid] = 1.0f / den[b * SS + q0 + tid];

  const int srow4 = lane >> 4;     // 0..3 row within 4-row staging group
  const int sg16  = lane & 15;     // slot index (16 chunks/row)
  const bf16* gA = Pp + ((size_t)b * SS + q0) * SS;
  const bf16* gB = Vt + ((size_t)b * DD + d0) * SS;

  f32x16 acc0 = {}, acc1 = {};

  for (int kc = 0; kc < SS; kc += 128) {
    __syncthreads();
#pragma unroll
    for (int j = 0; j < 8; ++j) {
      int row = w * 32 + j * 4 + srow4;
      gload_lds16(gA + (size_t)row * SS + kc + ((sg16 ^ (row & 7)) * 8),
                  At + (w * 32 + j * 4) * 128);
    }
#pragma unroll
    for (int j = 0; j < 4; ++j) {
      int row = w * 16 + j * 4 + srow4;
      gload_lds16(gB + (size_t)row * SS + kc + ((sg16 ^ (row & 7)) * 8),
                  Bt + (w * 16 + j * 4) * 128);
    }
    __syncthreads();
#pragma unroll
    for (int kk = 0; kk < 8; ++kk) {
      int c = kk * 2 + lh;          // 0..15
      int ra = w * 32 + l31;
      int rb0 = l31, rb1 = 32 + l31;
      bf16x8 af = *(const bf16x8*)&At[ra * 128 + ((c ^ (ra & 7)) << 3)];
      bf16x8 b0 = *(const bf16x8*)&Bt[rb0 * 128 + ((c ^ (rb0 & 7)) << 3)];
      bf16x8 b1 = *(const bf16x8*)&Bt[rb1 * 128 + ((c ^ (rb1 & 7)) << 3)];
      acc0 = __builtin_amdgcn_mfma_f32_32x32x16_bf16(af, b0, acc0, 0, 0, 0);
      acc1 = __builtin_amdgcn_mfma_f32_32x32x16_bf16(af, b1, acc1, 0, 0, 0);
    }
  }

  int qrow[16];
#pragma unroll
  for (int r = 0; r < 16; ++r) qrow[r] = (r & 3) + 8 * (r >> 2) + 4 * lh;

  float* Ob = out + ((size_t)b * SS + q0) * DD + d0;
#pragma unroll
  for (int r = 0; r < 16; ++r) {
    int row = w * 32 + qrow[r];
    float iv = dinv[row];
    float* Or = Ob + (size_t)row * DD;
    Or[l31]      = acc0[r] * iv;
    Or[32 + l31] = acc1[r] * iv;
  }
}

// ---------------- fallback (round-1 kernel, zero workspace) ----------------

#define QS_STRIDE 520
#define KS_STRIDE 72
#define VT_STRIDE 18
#define PS_STRIDE 136

__device__ __forceinline__ f32x16 qk_tile(const float* __restrict__ Kb,
                                          const bf16* __restrict__ Qsl,
                                          bf16* __restrict__ KVw,
                                          int l31, int lh8, int lane) {
  f32x16 acc = {};
  for (int dc = 0; dc < DD; dc += 64) {
#pragma unroll
    for (int i = 0; i < 8; ++i) {
      int f = i * 64 + lane;
      int row = f >> 4;
      int c4 = (f & 15) * 4;
      float4 v = *(const float4*)(Kb + row * DD + dc + c4);
      bf16x4 h = { (bf16)v.x, (bf16)v.y, (bf16)v.z, (bf16)v.w };
      *(bf16x4*)&KVw[row * KS_STRIDE + c4] = h;
    }
#pragma unroll
    for (int ks = 0; ks < 4; ++ks) {
      bf16x8 a  = *(const bf16x8*)&Qsl[l31 * QS_STRIDE + dc + ks * 16 + lh8];
      bf16x8 bb = *(const bf16x8*)&KVw[l31 * KS_STRIDE + ks * 16 + lh8];
      acc = __builtin_amdgcn_mfma_f32_32x32x16_bf16(a, bb, acc, 0, 0, 0);
    }
  }
  return acc;
}

__launch_bounds__(256, 1)
__global__ void nm_attn_kernel(const float* __restrict__ Qp,
                               const float* __restrict__ Kp,
                               const float* __restrict__ Vp,
                               float* __restrict__ Op) {
  __shared__ bf16 Qs[32 * QS_STRIDE];
  __shared__ bf16 KVu[4][32 * KS_STRIDE];
  __shared__ bf16 Psl[32 * PS_STRIDE];
  __shared__ float redA[4][32];
  __shared__ float redB[4][32];
  __shared__ float a0v[32], a1v[32], idv[32];

  const int tid  = threadIdx.x;
  const int w    = tid >> 6;
  const int lane = tid & 63;
  const int l31  = lane & 31;
  const int lh8  = (lane >> 5) * 8;
  const int b    = blockIdx.y;
  const int q0   = blockIdx.x * 32;

  {
    const float* Qbase = Qp + (size_t)(b * SS + q0) * DD;
#pragma unroll
    for (int i = 0; i < 16; ++i) {
      int f = i * 256 + tid;
      int row = f >> 7;
      int c4 = (f & 127) * 4;
      float4 v = *(const float4*)(Qbase + row * DD + c4);
      bf16x4 h = { (bf16)v.x, (bf16)v.y, (bf16)v.z, (bf16)v.w };
      *(bf16x4*)&Qs[row * QS_STRIDE + c4] = h;
    }
  }
  __syncthreads();

  int qrow[16];
#pragma unroll
  for (int r = 0; r < 16; ++r) qrow[r] = (r & 3) + 8 * (r >> 2) + 4 * (lane >> 5);

  float sumv[16], sqv[16];
#pragma unroll
  for (int r = 0; r < 16; ++r) { sumv[r] = 0.f; sqv[r] = 0.f; }

  for (int kt = 0; kt < 16; ++kt) {
    const float* Kb = Kp + (size_t)(b * SS + kt * 128 + w * 32) * DD;
    f32x16 acc = qk_tile(Kb, Qs, KVu[w], l31, lh8, lane);
#pragma unroll
    for (int r = 0; r < 16; ++r) {
      float s = acc[r] * SCALE;
      sumv[r] += s;
      sqv[r]  += s * s;
    }
  }

#pragma unroll
  for (int r = 0; r < 16; ++r) {
    float v1 = sumv[r], v2 = sqv[r];
#pragma unroll
    for (int m = 16; m >= 1; m >>= 1) {
      v1 += __shfl_xor(v1, m);
      v2 += __shfl_xor(v2, m);
    }
    if (l31 == 0) { redA[w][qrow[r]] = v1; redB[w][qrow[r]] = v2; }
  }
  __syncthreads();
  if (tid < 32) {
    float s  = redA[0][tid] + redA[1][tid] + redA[2][tid] + redA[3][tid];
    float sq = redB[0][tid] + redB[1][tid] + redB[2][tid] + redB[3][tid];
    float mean = s * (1.0f / 2048.0f);
    float var = (sq - 2048.0f * mean * mean) * (1.0f / 2047.0f);
    var = fmaxf(var, 0.0f);
    float istd = 1.0f / (sqrtf(var) + 1e-6f);
    a1v[tid] = istd * LOG2E;
    a0v[tid] = -mean * istd * LOG2E;
  }
  __syncthreads();

  float a0r[16], a1r[16], den[16];
#pragma unroll
  for (int r = 0; r < 16; ++r) {
    a0r[r] = a0v[qrow[r]];
    a1r[r] = a1v[qrow[r]];
    den[r] = 0.f;
  }

  f32x16 Oa[4] = {};

  for (int kt = 0; kt < 16; ++kt) {
    const float* Kb = Kp + (size_t)(b * SS + kt * 128 + w * 32) * DD;
    f32x16 acc = qk_tile(Kb, Qs, KVu[w], l31, lh8, lane);

    __syncthreads();
#pragma unroll
    for (int r = 0; r < 16; ++r) {
      float s = acc[r] * SCALE;
      float p = exp2f(fmaf(s, a1r[r], a0r[r]));
      den[r] += p;
      Psl[qrow[r] * PS_STRIDE + w * 32 + l31] = (bf16)p;
    }
    __syncthreads();

    const float* Vb = Vp + (size_t)(b * SS + kt * 128) * DD + w * 128 + 2 * lane;
    bf16* Vts = KVu[w];
    const int d0 = 2 * lane;
    for (int ks2 = 0; ks2 < 8; ++ks2) {
      const float* Vk = Vb + ks2 * 16 * DD;
#pragma unroll
      for (int i = 0; i < 8; ++i) {
        float2 va = *(const float2*)(Vk + (2 * i) * DD);
        float2 vc = *(const float2*)(Vk + (2 * i + 1) * DD);
        bf16x2 h0 = { (bf16)va.x, (bf16)vc.x };
        bf16x2 h1 = { (bf16)va.y, (bf16)vc.y };
        *(bf16x2*)&Vts[d0 * VT_STRIDE + 2 * i] = h0;
        *(bf16x2*)&Vts[(d0 + 1) * VT_STRIDE + 2 * i] = h1;
      }
      bf16x8 aP = *(const bf16x8*)&Psl[l31 * PS_STRIDE + ks2 * 16 + lh8];
#pragma unroll
      for (int dt = 0; dt < 4; ++dt) {
        const bf16* vr = &Vts[(dt * 32 + l31) * VT_STRIDE + lh8];
        bf16x2 e0 = *(const bf16x2*)(vr + 0);
        bf16x2 e1 = *(const bf16x2*)(vr + 2);
        bf16x2 e2 = *(const bf16x2*)(vr + 4);
        bf16x2 e3 = *(const bf16x2*)(vr + 6);
        bf16x8 bV = { e0.x, e0.y, e1.x, e1.y, e2.x, e2.y, e3.x, e3.y };
        Oa[dt] = __builtin_amdgcn_mfma_f32_32x32x16_bf16(aP, bV, Oa[dt], 0, 0, 0);
      }
    }
  }

#pragma unroll
  for (int r = 0; r < 16; ++r) {
    float v1 = den[r];
#pragma unroll
    for (int m = 16; m >= 1; m >>= 1) v1 += __shfl_xor(v1, m);
    if (l31 == 0) redA[w][qrow[r]] = v1;
  }
  __syncthreads();
  if (tid < 32) {
    float t = redA[0][tid] + redA[1][tid] + redA[2][tid] + redA[3][tid];
    idv[tid] = 1.0f / t;
  }
  __syncthreads();

  float idr[16];
#pragma unroll
  for (int r = 0; r < 16; ++r) idr[r] = idv[qrow[r]];

  float* Ob = Op + (size_t)(b * SS + q0) * DD + w * 128;
#pragma unroll
  for (int dt = 0; dt < 4; ++dt) {
#pragma unroll
    for (int r = 0; r < 16; ++r) {
      Ob[qrow[r] * DD + dt * 32 + l31] = Oa[dt][r] * idr[r];
    }
  }
}

// ---------------- launcher ----------------

extern "C" void kernel_launch(void* const* d_in, const int* in_sizes, int n_in,
                              void* d_out, int out_size, void* d_ws, size_t ws_size,
                              hipStream_t stream) {
  const float* Q = (const float*)d_in[0];
  const float* K = (const float*)d_in[1];
  const float* V = (const float*)d_in[2];
  float* out = (float*)d_out;
  (void)in_sizes; (void)n_in; (void)out_size;

  const size_t E  = (size_t)BB * SS * DD;   // 4,194,304 elems / tensor
  const size_t SE = (size_t)BB * SS * SS;   // 16,777,216 score elems

  // ws layout: [Qb bf16 E][Kb bf16 E][Vt bf16 E][S f16 SE][P bf16 SE][den B*S f32]
  const size_t off_Kb  = E * sizeof(bf16);
  const size_t off_Vt  = off_Kb + E * sizeof(bf16);
  const size_t off_S   = off_Vt + E * sizeof(bf16);
  const size_t off_P   = off_S + SE * sizeof(f16);
  const size_t off_den = off_P + SE * sizeof(bf16);
  const size_t need    = off_den + (size_t)BB * SS * sizeof(float);  // ~92.3 MB

  if (ws_size >= need) {
    char* ws = (char*)d_ws;
    bf16*  Qb  = (bf16*)ws;
    bf16*  Kb  = (bf16*)(ws + off_Kb);
    bf16*  Vt  = (bf16*)(ws + off_Vt);
    f16*   Sp  = (f16*)(ws + off_S);
    bf16*  Pp  = (bf16*)(ws + off_P);
    float* den = (float*)(ws + off_den);

    prep_kernel<<<2048 + 1024, 256, 0, stream>>>(Q, K, V, Qb, Kb, Vt);
    qk_gemm_kernel<<<dim3(SS / 128, SS / 128, BB), 256, 0, stream>>>(Qb, Kb, Sp);
    softmax_kernel<<<dim3(SS, BB), 256, 0, stream>>>(Sp, Pp, den);
    pv_gemm_kernel<<<dim3(SS / 128, DD / 64, BB), 256, 0, stream>>>(Pp, Vt, den, out);
  } else {
    nm_attn_kernel<<<dim3(SS / 32, BB), dim3(256, 1, 1), 0, stream>>>(Q, K, V, out);
  }
}